// Round 1
// baseline (223.551 us; speedup 1.0000x reference)
//
#include <hip/hip_runtime.h>

// MultiScaleRoIAlign: 4 FPN levels (fp32 NCHW), 512 RoIs, 7x7 out, SR=2,
// aligned=False, torchvision semantics. Only the assigned level is computed.

#define OUT_HW 7
#define NBINS 49          // 7*7
#define NCH 256
#define RPB 256           // rois per image (boxes0 / boxes1)

__global__ __launch_bounds__(256) void msroi_kernel(
    const float* __restrict__ f0, const float* __restrict__ f1,
    const float* __restrict__ f2, const float* __restrict__ f3,
    const float* __restrict__ boxes0, const float* __restrict__ boxes1,
    float* __restrict__ out)
{
    __shared__ float lds_out[NCH * NBINS];   // 50176 B

    const int r    = blockIdx.x;       // roi index 0..511
    const int tid  = threadIdx.x;      // 0..255
    const int lane = tid & 63;
    const int wid  = tid >> 6;         // wave id 0..3 -> channel group

    // ---- per-roi metadata (uniform across block, recomputed per thread) ----
    const int b = (r < RPB) ? 0 : 1;
    const float* bx = (b == 0) ? (boxes0 + (size_t)r * 4)
                               : (boxes1 + (size_t)(r - RPB) * 4);
    const float x1b = bx[0], y1b = bx[1], x2b = bx[2], y2b = bx[3];

    const float area = (x2b - x1b) * (y2b - y1b);
    const float s    = sqrtf(area);
    const float tgt  = floorf(4.0f + log2f(s / 224.0f) + 1e-6f);
    const float lvlf = fminf(fmaxf(tgt, 2.0f), 5.0f);
    const int   lvl  = (int)lvlf - 2;          // 0..3

    int H, W;
    const float* feat;
    float scale;
    switch (lvl) {
      case 0:  feat = f0; H = 200; W = 200; scale = 0.25f;    break;
      case 1:  feat = f1; H = 100; W = 100; scale = 0.125f;   break;
      case 2:  feat = f2; H = 50;  W = 50;  scale = 0.0625f;  break;
      default: feat = f3; H = 25;  W = 25;  scale = 0.03125f; break;
    }
    const int HW = H * W;

    const float x1 = x1b * scale, y1 = y1b * scale;
    const float x2 = x2b * scale, y2 = y2b * scale;
    const float roi_w = fmaxf(x2 - x1, 1.0f);
    const float roi_h = fmaxf(y2 - y1, 1.0f);
    const float bin_w = roi_w / 7.0f;
    const float bin_h = roi_h / 7.0f;

    // ---- per-lane bin: precompute 16 (offset, weight) taps ----
    const bool active = (lane < NBINS);
    const int  binid  = active ? lane : 0;
    const int  oh = binid / 7, ow = binid % 7;

    int   offs[16];
    float wts[16];
    {
      int t = 0;
      #pragma unroll
      for (int sy = 0; sy < 2; ++sy) {
        const float iy = (float)(oh * 2 + sy);
        const float yy = y1 + ((iy + 0.5f) * 0.5f) * bin_h;   // gy = (i+0.5)/SR
        const float vy = (yy > -1.0f && yy < (float)H) ? 1.0f : 0.0f;
        const float yc = fmaxf(yy, 0.0f);
        const int   yl = min((int)yc, H - 1);                 // floor of nonneg
        const int   yh = min(yl + 1, H - 1);
        const float fy = (yl >= H - 1) ? 0.0f : (yc - (float)yl);
        const float ay0 = vy * (1.0f - fy), ay1 = vy * fy;
        #pragma unroll
        for (int sx = 0; sx < 2; ++sx) {
          const float ix = (float)(ow * 2 + sx);
          const float xx = x1 + ((ix + 0.5f) * 0.5f) * bin_w;
          const float vx = (xx > -1.0f && xx < (float)W) ? 1.0f : 0.0f;
          const float xc = fmaxf(xx, 0.0f);
          const int   xl = min((int)xc, W - 1);
          const int   xh = min(xl + 1, W - 1);
          const float fx = (xl >= W - 1) ? 0.0f : (xc - (float)xl);
          const float ax0 = vx * (1.0f - fx), ax1 = vx * fx;
          offs[t] = yl * W + xl;  wts[t] = ay0 * ax0;  ++t;
          offs[t] = yl * W + xh;  wts[t] = ay0 * ax1;  ++t;
          offs[t] = yh * W + xl;  wts[t] = ay1 * ax0;  ++t;
          offs[t] = yh * W + xh;  wts[t] = ay1 * ax1;  ++t;
        }
      }
      if (!active) {
        #pragma unroll
        for (int k = 0; k < 16; ++k) { offs[k] = 0; wts[k] = 0.0f; }
      }
    }

    // ---- channel loop: wave `wid` handles channels [wid*64, wid*64+64) ----
    const float* fb = feat + (size_t)b * NCH * HW + (size_t)wid * 64 * HW;
    for (int ci = 0; ci < 64; ++ci) {
      const float* fc = fb + (size_t)ci * HW;
      float acc = 0.0f;
      #pragma unroll
      for (int k = 0; k < 16; ++k)
        acc += wts[k] * fc[offs[k]];
      if (active)
        lds_out[(wid * 64 + ci) * NBINS + binid] = acc * 0.25f;
    }

    __syncthreads();

    // ---- coalesced output write: [r, c, oh, ow] contiguous 12544 floats ----
    const size_t obase = (size_t)r * (NCH * NBINS);
    #pragma unroll 4
    for (int i = tid; i < NCH * NBINS; i += 256)
      out[obase + i] = lds_out[i];
}

extern "C" void kernel_launch(void* const* d_in, const int* in_sizes, int n_in,
                              void* d_out, int out_size, void* d_ws, size_t ws_size,
                              hipStream_t stream) {
    const float* f0 = (const float*)d_in[0];
    const float* f1 = (const float*)d_in[1];
    const float* f2 = (const float*)d_in[2];
    const float* f3 = (const float*)d_in[3];
    const float* b0 = (const float*)d_in[4];
    const float* b1 = (const float*)d_in[5];
    float* out = (float*)d_out;

    msroi_kernel<<<dim3(512), dim3(256), 0, stream>>>(f0, f1, f2, f3, b0, b1, out);
}